// Round 1
// baseline (1209.493 us; speedup 1.0000x reference)
//
#include <hip/hip_runtime.h>

#define NN 50000
#define NE 800000
#define NH 64
#define NG 500

// ---------------- degree / normalization ----------------

__global__ __launch_bounds__(256) void k_init_deg(float* __restrict__ deg) {
  int i = blockIdx.x * 256 + threadIdx.x;
  if (i < NN) deg[i] = 1.0f;  // self-loop
}

__global__ __launch_bounds__(256) void k_count_deg(const int* __restrict__ dst, float* __restrict__ deg) {
  int e = blockIdx.x * 256 + threadIdx.x;
  if (e < NE) atomicAdd(&deg[dst[e]], 1.0f);
}

__global__ __launch_bounds__(256) void k_dinv(float* __restrict__ deg) {
  int i = blockIdx.x * 256 + threadIdx.x;
  if (i < NN) deg[i] = rsqrtf(deg[i]);  // deg >= 1 always
}

// ---------------- encoder: X0 = [x|pos] @ enc_W + enc_b ----------------

__global__ __launch_bounds__(256) void k_encoder(const float* __restrict__ x, const float* __restrict__ pos,
                                                 const float* __restrict__ W, const float* __restrict__ b,
                                                 float* __restrict__ X0) {
  __shared__ float Ws[16 * 64];
  __shared__ float bs[64];
  int t = threadIdx.x;
  for (int i = t; i < 1024; i += 256) Ws[i] = W[i];
  if (t < 64) bs[t] = b[t];
  __syncthreads();
  int n = blockIdx.x * 4 + (t >> 6);
  int h = t & 63;
  if (n >= NN) return;
  float acc = bs[h];
#pragma unroll
  for (int f = 0; f < 14; f++) acc += x[n * 14 + f] * Ws[f * 64 + h];
  acc += pos[n * 2 + 0] * Ws[14 * 64 + h];
  acc += pos[n * 2 + 1] * Ws[15 * 64 + h];
  X0[n * 64 + h] = acc;
}

// ---------------- fused dual GEMM + epilogue ----------------
// hW  = relu?(X) @ conv_W
// agg = relu?(X) @ res_W + res_b + conv_b + dinv[n]^2 * hW[n]   (self-loop folded in)
// Tile: 128 nodes x 64 h per block (256 threads, 8n x 4h register tile).
// LDS: X tile XOR-swizzled (2-way max aliasing == free) + both W mats = 64 KB exactly.

__global__ __launch_bounds__(256) void k_gemm_dual(const float* __restrict__ Xin,
                                                   const float* __restrict__ Wc, const float* __restrict__ Wr,
                                                   const float* __restrict__ cb, const float* __restrict__ rb,
                                                   const float* __restrict__ dinv,
                                                   float* __restrict__ hW, float* __restrict__ agg,
                                                   int apply_relu) {
  __shared__ float Xs[128 * 64];
  __shared__ float Wcs[64 * 64];
  __shared__ float Wrs[64 * 64];
  int t = threadIdx.x;
  for (int i = t; i < 4096; i += 256) { Wcs[i] = Wc[i]; Wrs[i] = Wr[i]; }
  int n0 = blockIdx.x * 128;
#pragma unroll
  for (int i = 0; i < 8; i++) {
    int idx = t + i * 256;        // float4 index in 128x64 tile (2048 total)
    int n = idx >> 4;             // 16 float4 per row
    int kg = (idx & 15) << 2;     // k offset of float4
    float4 v = make_float4(0.f, 0.f, 0.f, 0.f);
    int gn = n0 + n;
    if (gn < NN) v = *(const float4*)(Xin + gn * 64 + kg);
    if (apply_relu) {
      v.x = fmaxf(v.x, 0.f); v.y = fmaxf(v.y, 0.f);
      v.z = fmaxf(v.z, 0.f); v.w = fmaxf(v.w, 0.f);
    }
    int sw = ((n >> 3) & 3) << 4;  // XOR swizzle keeps banks <=2-way on reads
    *(float4*)(Xs + n * 64 + (kg ^ sw)) = v;
  }
  __syncthreads();

  int hg = (t & 15) << 2;   // h0 (4 consecutive h)
  int ng = t >> 4;          // node group
  int nb = ng << 3;         // local node base (8 nodes)
  int swz = (ng & 3) << 4;  // matches write swizzle: ((node>>3)&3)<<4, i<8

  float aC[8][4] = {};
  float aR[8][4] = {};
#pragma unroll 4
  for (int k = 0; k < 64; k++) {
    float4 wc = *(const float4*)(Wcs + k * 64 + hg);
    float4 wr = *(const float4*)(Wrs + k * 64 + hg);
    int kk = k ^ swz;
#pragma unroll
    for (int i = 0; i < 8; i++) {
      float xv = Xs[(nb + i) * 64 + kk];
      aC[i][0] += xv * wc.x; aC[i][1] += xv * wc.y; aC[i][2] += xv * wc.z; aC[i][3] += xv * wc.w;
      aR[i][0] += xv * wr.x; aR[i][1] += xv * wr.y; aR[i][2] += xv * wr.z; aR[i][3] += xv * wr.w;
    }
  }

  float4 cbv = *(const float4*)(cb + hg);
  float4 rbv = *(const float4*)(rb + hg);
#pragma unroll
  for (int i = 0; i < 8; i++) {
    int n = n0 + nb + i;
    if (n < NN) {
      float dv = dinv[n];
      float d2 = dv * dv;
      float4 hv = make_float4(aC[i][0], aC[i][1], aC[i][2], aC[i][3]);
      *(float4*)(hW + n * 64 + hg) = hv;
      float4 av;
      av.x = aR[i][0] + rbv.x + cbv.x + d2 * hv.x;
      av.y = aR[i][1] + rbv.y + cbv.y + d2 * hv.y;
      av.z = aR[i][2] + rbv.z + cbv.z + d2 * hv.z;
      av.w = aR[i][3] + rbv.w + cbv.w + d2 * hv.w;
      *(float4*)(agg + n * 64 + hg) = av;
    }
  }
}

// ---------------- edge scatter: agg[dst] += hW[src] * dinv[src]*dinv[dst] ----------------

__global__ __launch_bounds__(256) void k_scatter(const int* __restrict__ src, const int* __restrict__ dst,
                                                 const float* __restrict__ dinv, const float* __restrict__ hW,
                                                 float* __restrict__ agg) {
  int idx = blockIdx.x * 256 + threadIdx.x;
  int e = idx >> 6;
  int h = idx & 63;
  if (e < NE) {
    int s = src[e], d = dst[e];
    float w = dinv[s] * dinv[d];
    atomicAdd(&agg[d * 64 + h], hW[s * 64 + h] * w);
  }
}

// ---------------- decoder + graph pooling ----------------
// Xo[n] = relu(X[n]) . dec_W + dec_b ; out[g] += Xo[n]

__global__ __launch_bounds__(256) void k_decode(const float* __restrict__ Xf, const int* __restrict__ batch,
                                                const float* __restrict__ decW, const float* __restrict__ decb,
                                                float* __restrict__ out) {
  int t = threadIdx.x;
  int lane = t & 63;
  int n = blockIdx.x * 4 + (t >> 6);
  if (n >= NN) return;
  float v = fmaxf(Xf[n * 64 + lane], 0.f) * decW[lane];
#pragma unroll
  for (int off = 32; off > 0; off >>= 1) v += __shfl_down(v, off, 64);
  if (lane == 0) atomicAdd(&out[batch[n]], v + decb[0]);
}

// ---------------- launch ----------------

extern "C" void kernel_launch(void* const* d_in, const int* in_sizes, int n_in,
                              void* d_out, int out_size, void* d_ws, size_t ws_size,
                              hipStream_t stream) {
  (void)in_sizes; (void)n_in; (void)out_size; (void)ws_size;
  const float* x     = (const float*)d_in[0];
  const float* pos   = (const float*)d_in[1];
  const int*   ei    = (const int*)d_in[2];
  const int*   batch = (const int*)d_in[3];
  const float* encW  = (const float*)d_in[4];
  const float* encb  = (const float*)d_in[5];
  const float* convW = (const float*)d_in[6];
  const float* convb = (const float*)d_in[7];
  const float* resW  = (const float*)d_in[8];
  const float* resb  = (const float*)d_in[9];
  const float* decW  = (const float*)d_in[10];
  const float* decb  = (const float*)d_in[11];
  float* out = (float*)d_out;

  const int* src = ei;       // edge_index[0]
  const int* dst = ei + NE;  // edge_index[1]

  float* ws   = (float*)d_ws;
  float* dinv = ws;                    // NN (rounded region: 50048)
  float* bufA = ws + 50048;            // NN*NH
  float* bufB = bufA + NN * NH;        // NN*NH
  float* bufC = bufB + NN * NH;        // NN*NH

  hipMemsetAsync(d_out, 0, NG * sizeof(float), stream);
  k_init_deg<<<(NN + 255) / 256, 256, 0, stream>>>(dinv);
  k_count_deg<<<(NE + 255) / 256, 256, 0, stream>>>(dst, dinv);
  k_dinv<<<(NN + 255) / 256, 256, 0, stream>>>(dinv);
  k_encoder<<<(NN + 3) / 4, 256, 0, stream>>>(x, pos, encW, encb, bufA);

  float* Xc = bufA;
  float* hWb = bufB;
  float* aggb = bufC;
  for (int l = 0; l < 5; l++) {
    k_gemm_dual<<<(NN + 127) / 128, 256, 0, stream>>>(Xc, convW, resW, convb, resb, dinv, hWb, aggb, l > 0 ? 1 : 0);
    k_scatter<<<(NE * 64) / 256, 256, 0, stream>>>(src, dst, dinv, hWb, aggb);
    // rotate: next X = agg ; old X becomes scratch hW ; old hW becomes scratch agg
    float* tmp = Xc; Xc = aggb; aggb = hWb; hWb = tmp;
  }
  k_decode<<<(NN + 3) / 4, 256, 0, stream>>>(Xc, batch, decW, decb, out);
}

// Round 2
// 576.626 us; speedup vs baseline: 2.0975x; 2.0975x over previous
//
#include <hip/hip_runtime.h>

#define NN 50000
#define NE 800000
#define NH 64
#define NG 500
#define NPAD 50176   // 196*256

// ---------------- degree histogram / normalization ----------------

__global__ __launch_bounds__(256) void k_hist(const int* __restrict__ dst, int* __restrict__ deg) {
  int e = blockIdx.x * 256 + threadIdx.x;
  if (e < NE) atomicAdd(&deg[dst[e]], 1);
}

__global__ __launch_bounds__(256) void k_dinv(const int* __restrict__ deg, float* __restrict__ dinv) {
  int i = blockIdx.x * 256 + threadIdx.x;
  if (i < NN) dinv[i] = rsqrtf((float)(deg[i] + 1));  // +1 self-loop
}

// ---------------- CSR build: scan + fill ----------------

__global__ __launch_bounds__(256) void k_scanA(const int* __restrict__ deg, int* __restrict__ bsum) {
  __shared__ int part[4];
  int i = blockIdx.x * 256 + threadIdx.x;
  int v = deg[i];  // region zeroed to NPAD
#pragma unroll
  for (int off = 32; off > 0; off >>= 1) v += __shfl_down(v, off, 64);
  if ((threadIdx.x & 63) == 0) part[threadIdx.x >> 6] = v;
  __syncthreads();
  if (threadIdx.x == 0) bsum[blockIdx.x] = part[0] + part[1] + part[2] + part[3];
}

__global__ __launch_bounds__(256) void k_scanB(int* __restrict__ bsum) {
  __shared__ int s[256];
  int t = threadIdx.x;
  int v = (t < 196) ? bsum[t] : 0;
  s[t] = v;
  __syncthreads();
#pragma unroll
  for (int off = 1; off < 256; off <<= 1) {
    int x = (t >= off) ? s[t - off] : 0;
    __syncthreads();
    s[t] += x;
    __syncthreads();
  }
  if (t < 196) bsum[t] = s[t] - v;  // exclusive
}

__global__ __launch_bounds__(256) void k_scanC(const int* __restrict__ deg, const int* __restrict__ bsum,
                                               int* __restrict__ rowptr, int* __restrict__ cursor) {
  __shared__ int s[256];
  int t = threadIdx.x;
  int i = blockIdx.x * 256 + t;
  int v = deg[i];
  s[t] = v;
  __syncthreads();
#pragma unroll
  for (int off = 1; off < 256; off <<= 1) {
    int x = (t >= off) ? s[t - off] : 0;
    __syncthreads();
    s[t] += x;
    __syncthreads();
  }
  int row = bsum[blockIdx.x] + s[t] - v;  // exclusive prefix; deg[i>=NN]==0 so rowptr[NN]==NE
  rowptr[i] = row;
  cursor[i] = row;
}

__global__ __launch_bounds__(256) void k_fill(const int* __restrict__ src, const int* __restrict__ dst,
                                              const float* __restrict__ dinv, int* __restrict__ cursor,
                                              int* __restrict__ col, float* __restrict__ wgt) {
  int e = blockIdx.x * 256 + threadIdx.x;
  if (e < NE) {
    int s = src[e], d = dst[e];
    int p = atomicAdd(&cursor[d], 1);
    col[p] = s;
    wgt[p] = dinv[s] * dinv[d];
  }
}

// ---------------- encoder: X0 = [x|pos] @ enc_W + enc_b ----------------

__global__ __launch_bounds__(256) void k_encoder(const float* __restrict__ x, const float* __restrict__ pos,
                                                 const float* __restrict__ W, const float* __restrict__ b,
                                                 float* __restrict__ X0) {
  __shared__ float Ws[16 * 64];
  __shared__ float bs[64];
  int t = threadIdx.x;
  for (int i = t; i < 1024; i += 256) Ws[i] = W[i];
  if (t < 64) bs[t] = b[t];
  __syncthreads();
  int n = blockIdx.x * 4 + (t >> 6);
  int h = t & 63;
  if (n >= NN) return;
  float acc = bs[h];
#pragma unroll
  for (int f = 0; f < 14; f++) acc += x[n * 14 + f] * Ws[f * 64 + h];
  acc += pos[n * 2 + 0] * Ws[14 * 64 + h];
  acc += pos[n * 2 + 1] * Ws[15 * 64 + h];
  X0[n * 64 + h] = acc;
}

// ---------------- fused dual GEMM + epilogue ----------------
// hW  = relu?(X) @ conv_W
// agg = relu?(X) @ res_W + res_b + conv_b + dinv[n]^2 * hW[n]   (self-loop folded in)
// Swizzle ((n>>3)&7)<<2: 16 broadcast X-read addrs spread over 8 bank-quads, 2-way (free).

__global__ __launch_bounds__(256) void k_gemm_dual(const float* __restrict__ Xin,
                                                   const float* __restrict__ Wc, const float* __restrict__ Wr,
                                                   const float* __restrict__ cb, const float* __restrict__ rb,
                                                   const float* __restrict__ dinv,
                                                   float* __restrict__ hW, float* __restrict__ agg,
                                                   int apply_relu) {
  __shared__ float Xs[128 * 64];
  __shared__ float Wcs[64 * 64];
  __shared__ float Wrs[64 * 64];
  int t = threadIdx.x;
  for (int i = t; i < 4096; i += 256) { Wcs[i] = Wc[i]; Wrs[i] = Wr[i]; }
  int n0 = blockIdx.x * 128;
#pragma unroll
  for (int i = 0; i < 8; i++) {
    int idx = t + i * 256;        // float4 index in 128x64 tile (2048 total)
    int n = idx >> 4;             // 16 float4 per row
    int kg = (idx & 15) << 2;     // k offset of float4
    float4 v = make_float4(0.f, 0.f, 0.f, 0.f);
    int gn = n0 + n;
    if (gn < NN) v = *(const float4*)(Xin + gn * 64 + kg);
    if (apply_relu) {
      v.x = fmaxf(v.x, 0.f); v.y = fmaxf(v.y, 0.f);
      v.z = fmaxf(v.z, 0.f); v.w = fmaxf(v.w, 0.f);
    }
    int sw = ((n >> 3) & 7) << 2;  // bank swizzle (float4-preserving)
    *(float4*)(Xs + n * 64 + (kg ^ sw)) = v;
  }
  __syncthreads();

  int hg = (t & 15) << 2;   // h0 (4 consecutive h)
  int ng = t >> 4;          // node group
  int nb = ng << 3;         // local node base (8 nodes)
  int swz = (ng & 7) << 2;  // matches write swizzle: rows nb..nb+7 all have row>>3 == ng

  float aC[8][4] = {};
  float aR[8][4] = {};
#pragma unroll 4
  for (int k = 0; k < 64; k++) {
    float4 wc = *(const float4*)(Wcs + k * 64 + hg);
    float4 wr = *(const float4*)(Wrs + k * 64 + hg);
    int kk = k ^ swz;
#pragma unroll
    for (int i = 0; i < 8; i++) {
      float xv = Xs[(nb + i) * 64 + kk];
      aC[i][0] += xv * wc.x; aC[i][1] += xv * wc.y; aC[i][2] += xv * wc.z; aC[i][3] += xv * wc.w;
      aR[i][0] += xv * wr.x; aR[i][1] += xv * wr.y; aR[i][2] += xv * wr.z; aR[i][3] += xv * wr.w;
    }
  }

  float4 cbv = *(const float4*)(cb + hg);
  float4 rbv = *(const float4*)(rb + hg);
#pragma unroll
  for (int i = 0; i < 8; i++) {
    int n = n0 + nb + i;
    if (n < NN) {
      float dv = dinv[n];
      float d2 = dv * dv;
      float4 hv = make_float4(aC[i][0], aC[i][1], aC[i][2], aC[i][3]);
      *(float4*)(hW + n * 64 + hg) = hv;
      float4 av;
      av.x = aR[i][0] + rbv.x + cbv.x + d2 * hv.x;
      av.y = aR[i][1] + rbv.y + cbv.y + d2 * hv.y;
      av.z = aR[i][2] + rbv.z + cbv.z + d2 * hv.z;
      av.w = aR[i][3] + rbv.w + cbv.w + d2 * hv.w;
      *(float4*)(agg + n * 64 + hg) = av;
    }
  }
}

// ---------------- CSR gather: agg[n] += sum_e wgt[e] * hW[col[e]] ----------------
// One 64-lane wave per dst node; lane = h. col/wgt are wave-uniform -> scalar loads.

__global__ __launch_bounds__(256) void k_gather(const int* __restrict__ rowptr, const int* __restrict__ col,
                                                const float* __restrict__ wgt, const float* __restrict__ hW,
                                                float* __restrict__ agg) {
  int lane = threadIdx.x & 63;
  int n = __builtin_amdgcn_readfirstlane(blockIdx.x * 4 + (threadIdx.x >> 6));
  int st = rowptr[n];
  int en = rowptr[n + 1];
  float acc = agg[n * 64 + lane];
  int e = st;
  for (; e + 1 < en; e += 2) {
    int s0 = col[e], s1 = col[e + 1];
    float w0 = wgt[e], w1 = wgt[e + 1];
    acc += w0 * hW[s0 * 64 + lane];
    acc += w1 * hW[s1 * 64 + lane];
  }
  if (e < en) acc += wgt[e] * hW[col[e] * 64 + lane];
  agg[n * 64 + lane] = acc;
}

// ---------------- decoder + graph pooling ----------------

__global__ __launch_bounds__(256) void k_decode(const float* __restrict__ Xf, const int* __restrict__ batch,
                                                const float* __restrict__ decW, const float* __restrict__ decb,
                                                float* __restrict__ out) {
  int t = threadIdx.x;
  int lane = t & 63;
  int n = blockIdx.x * 4 + (t >> 6);
  if (n >= NN) return;
  float v = fmaxf(Xf[n * 64 + lane], 0.f) * decW[lane];
#pragma unroll
  for (int off = 32; off > 0; off >>= 1) v += __shfl_down(v, off, 64);
  if (lane == 0) atomicAdd(&out[batch[n]], v + decb[0]);
}

// ---------------- launch ----------------

extern "C" void kernel_launch(void* const* d_in, const int* in_sizes, int n_in,
                              void* d_out, int out_size, void* d_ws, size_t ws_size,
                              hipStream_t stream) {
  (void)in_sizes; (void)n_in; (void)out_size; (void)ws_size;
  const float* x     = (const float*)d_in[0];
  const float* pos   = (const float*)d_in[1];
  const int*   ei    = (const int*)d_in[2];
  const int*   batch = (const int*)d_in[3];
  const float* encW  = (const float*)d_in[4];
  const float* encb  = (const float*)d_in[5];
  const float* convW = (const float*)d_in[6];
  const float* convb = (const float*)d_in[7];
  const float* resW  = (const float*)d_in[8];
  const float* resb  = (const float*)d_in[9];
  const float* decW  = (const float*)d_in[10];
  const float* decb  = (const float*)d_in[11];
  float* out = (float*)d_out;

  const int* src = ei;       // edge_index[0]
  const int* dst = ei + NE;  // edge_index[1]

  // workspace layout (4-byte elems)
  float* ws     = (float*)d_ws;
  float* dinv   = ws;                        // [NPAD]
  int*   deg    = (int*)(ws + NPAD);         // [NPAD]
  int*   rowptr = (int*)(ws + 2 * NPAD);     // [NPAD+1] (rowptr[NN]=NE falls out of scan)
  int*   cursor = (int*)(ws + 3 * NPAD + 256);
  int*   bsum   = (int*)(ws + 4 * NPAD + 256);  // [256]
  int*   col    = (int*)(ws + 4 * NPAD + 512);  // [NE]
  float* wgt    = (float*)(col + NE);           // [NE]
  float* bufA   = wgt + NE;                     // [NN*NH]
  float* bufB   = bufA + NN * NH;
  float* bufC   = bufB + NN * NH;

  hipMemsetAsync(d_out, 0, NG * sizeof(float), stream);
  hipMemsetAsync(deg, 0, NPAD * sizeof(int), stream);

  k_hist<<<(NE + 255) / 256, 256, 0, stream>>>(dst, deg);
  k_dinv<<<(NN + 255) / 256, 256, 0, stream>>>(deg, dinv);
  k_scanA<<<NPAD / 256, 256, 0, stream>>>(deg, bsum);
  k_scanB<<<1, 256, 0, stream>>>(bsum);
  k_scanC<<<NPAD / 256, 256, 0, stream>>>(deg, bsum, rowptr, cursor);
  k_fill<<<(NE + 255) / 256, 256, 0, stream>>>(src, dst, dinv, cursor, col, wgt);

  k_encoder<<<(NN + 3) / 4, 256, 0, stream>>>(x, pos, encW, encb, bufA);

  float* Xc = bufA;
  float* hWb = bufB;
  float* aggb = bufC;
  for (int l = 0; l < 5; l++) {
    k_gemm_dual<<<(NN + 127) / 128, 256, 0, stream>>>(Xc, convW, resW, convb, resb, dinv, hWb, aggb, l > 0 ? 1 : 0);
    k_gather<<<NN / 4, 256, 0, stream>>>(rowptr, col, wgt, hWb, aggb);
    float* tmp = Xc; Xc = aggb; aggb = hWb; hWb = tmp;
  }
  k_decode<<<(NN + 3) / 4, 256, 0, stream>>>(Xc, batch, decW, decb, out);
}

// Round 3
// 468.081 us; speedup vs baseline: 2.5839x; 1.2319x over previous
//
#include <hip/hip_runtime.h>

#define NN 50000
#define NE 800000
#define NH 64
#define NG 500
#define NPAD 50176   // 196*256

// ---------------- degree histogram / normalization ----------------

__global__ __launch_bounds__(256) void k_hist(const int* __restrict__ dst, int* __restrict__ deg) {
  int e = blockIdx.x * 256 + threadIdx.x;
  if (e < NE) atomicAdd(&deg[dst[e]], 1);
}

__global__ __launch_bounds__(256) void k_dinv(const int* __restrict__ deg, float* __restrict__ dinv) {
  int i = blockIdx.x * 256 + threadIdx.x;
  if (i < NN) dinv[i] = rsqrtf((float)(deg[i] + 1));  // +1 self-loop
}

// ---------------- CSR build: scan + fill ----------------

__global__ __launch_bounds__(256) void k_scanA(const int* __restrict__ deg, int* __restrict__ bsum) {
  __shared__ int part[4];
  int i = blockIdx.x * 256 + threadIdx.x;
  int v = deg[i];  // region zeroed to NPAD
#pragma unroll
  for (int off = 32; off > 0; off >>= 1) v += __shfl_down(v, off, 64);
  if ((threadIdx.x & 63) == 0) part[threadIdx.x >> 6] = v;
  __syncthreads();
  if (threadIdx.x == 0) bsum[blockIdx.x] = part[0] + part[1] + part[2] + part[3];
}

__global__ __launch_bounds__(256) void k_scanB(int* __restrict__ bsum) {
  __shared__ int s[256];
  int t = threadIdx.x;
  int v = (t < 196) ? bsum[t] : 0;
  s[t] = v;
  __syncthreads();
#pragma unroll
  for (int off = 1; off < 256; off <<= 1) {
    int x = (t >= off) ? s[t - off] : 0;
    __syncthreads();
    s[t] += x;
    __syncthreads();
  }
  if (t < 196) bsum[t] = s[t] - v;  // exclusive
}

__global__ __launch_bounds__(256) void k_scanC(const int* __restrict__ deg, const int* __restrict__ bsum,
                                               int* __restrict__ rowptr, int* __restrict__ cursor) {
  __shared__ int s[256];
  int t = threadIdx.x;
  int i = blockIdx.x * 256 + t;
  int v = deg[i];
  s[t] = v;
  __syncthreads();
#pragma unroll
  for (int off = 1; off < 256; off <<= 1) {
    int x = (t >= off) ? s[t - off] : 0;
    __syncthreads();
    s[t] += x;
    __syncthreads();
  }
  int row = bsum[blockIdx.x] + s[t] - v;  // exclusive prefix; deg[i>=NN]==0 so rowptr[NN]==NE
  rowptr[i] = row;
  cursor[i] = row;
}

__global__ __launch_bounds__(256) void k_fill(const int* __restrict__ src, const int* __restrict__ dst,
                                              const float* __restrict__ dinv, int* __restrict__ cursor,
                                              int* __restrict__ col, float* __restrict__ wgt) {
  int e = blockIdx.x * 256 + threadIdx.x;
  if (e < NE) {
    int s = src[e], d = dst[e];
    int p = atomicAdd(&cursor[d], 1);
    col[p] = s;
    wgt[p] = dinv[s] * dinv[d];
  }
}

// ---------------- graph segment pointers from sorted batch (no atomics) ----------------

__global__ __launch_bounds__(256) void k_gptr(const int* __restrict__ batch, int* __restrict__ gptr) {
  int i = blockIdx.x * 256 + threadIdx.x;
  if (i >= NN) return;
  int bi = batch[i];
  int bp = (i > 0) ? batch[i - 1] : -1;
  for (int g = bp + 1; g <= bi; g++) gptr[g] = i;
  if (i == NN - 1) {
    for (int g = bi + 1; g <= NG; g++) gptr[g] = NN;
  }
}

// ---------------- encoder: X0 = [x|pos] @ enc_W + enc_b ----------------

__global__ __launch_bounds__(256) void k_encoder(const float* __restrict__ x, const float* __restrict__ pos,
                                                 const float* __restrict__ W, const float* __restrict__ b,
                                                 float* __restrict__ X0) {
  __shared__ float Ws[16 * 64];
  __shared__ float bs[64];
  int t = threadIdx.x;
  for (int i = t; i < 1024; i += 256) Ws[i] = W[i];
  if (t < 64) bs[t] = b[t];
  __syncthreads();
  int n = blockIdx.x * 4 + (t >> 6);
  int h = t & 63;
  if (n >= NN) return;
  float acc = bs[h];
#pragma unroll
  for (int f = 0; f < 14; f++) acc += x[n * 14 + f] * Ws[f * 64 + h];
  acc += pos[n * 2 + 0] * Ws[14 * 64 + h];
  acc += pos[n * 2 + 1] * Ws[15 * 64 + h];
  X0[n * 64 + h] = acc;
}

// ---------------- fused dual GEMM + epilogue ----------------
// hW  = relu?(X) @ conv_W
// agg = relu?(X) @ res_W + res_b + conv_b + dinv[n]^2 * hW[n]   (self-loop folded in)

__global__ __launch_bounds__(256) void k_gemm_dual(const float* __restrict__ Xin,
                                                   const float* __restrict__ Wc, const float* __restrict__ Wr,
                                                   const float* __restrict__ cb, const float* __restrict__ rb,
                                                   const float* __restrict__ dinv,
                                                   float* __restrict__ hW, float* __restrict__ agg,
                                                   int apply_relu) {
  __shared__ float Xs[128 * 64];
  __shared__ float Wcs[64 * 64];
  __shared__ float Wrs[64 * 64];
  int t = threadIdx.x;
  for (int i = t; i < 4096; i += 256) { Wcs[i] = Wc[i]; Wrs[i] = Wr[i]; }
  int n0 = blockIdx.x * 128;
#pragma unroll
  for (int i = 0; i < 8; i++) {
    int idx = t + i * 256;        // float4 index in 128x64 tile (2048 total)
    int n = idx >> 4;             // 16 float4 per row
    int kg = (idx & 15) << 2;     // k offset of float4
    float4 v = make_float4(0.f, 0.f, 0.f, 0.f);
    int gn = n0 + n;
    if (gn < NN) v = *(const float4*)(Xin + gn * 64 + kg);
    if (apply_relu) {
      v.x = fmaxf(v.x, 0.f); v.y = fmaxf(v.y, 0.f);
      v.z = fmaxf(v.z, 0.f); v.w = fmaxf(v.w, 0.f);
    }
    int sw = ((n >> 3) & 7) << 2;  // bank swizzle (float4-preserving)
    *(float4*)(Xs + n * 64 + (kg ^ sw)) = v;
  }
  __syncthreads();

  int hg = (t & 15) << 2;   // h0 (4 consecutive h)
  int ng = t >> 4;          // node group
  int nb = ng << 3;         // local node base (8 nodes)
  int swz = (ng & 7) << 2;  // matches write swizzle: rows nb..nb+7 all have row>>3 == ng

  float aC[8][4] = {};
  float aR[8][4] = {};
#pragma unroll 4
  for (int k = 0; k < 64; k++) {
    float4 wc = *(const float4*)(Wcs + k * 64 + hg);
    float4 wr = *(const float4*)(Wrs + k * 64 + hg);
    int kk = k ^ swz;
#pragma unroll
    for (int i = 0; i < 8; i++) {
      float xv = Xs[(nb + i) * 64 + kk];
      aC[i][0] += xv * wc.x; aC[i][1] += xv * wc.y; aC[i][2] += xv * wc.z; aC[i][3] += xv * wc.w;
      aR[i][0] += xv * wr.x; aR[i][1] += xv * wr.y; aR[i][2] += xv * wr.z; aR[i][3] += xv * wr.w;
    }
  }

  float4 cbv = *(const float4*)(cb + hg);
  float4 rbv = *(const float4*)(rb + hg);
#pragma unroll
  for (int i = 0; i < 8; i++) {
    int n = n0 + nb + i;
    if (n < NN) {
      float dv = dinv[n];
      float d2 = dv * dv;
      float4 hv = make_float4(aC[i][0], aC[i][1], aC[i][2], aC[i][3]);
      *(float4*)(hW + n * 64 + hg) = hv;
      float4 av;
      av.x = aR[i][0] + rbv.x + cbv.x + d2 * hv.x;
      av.y = aR[i][1] + rbv.y + cbv.y + d2 * hv.y;
      av.z = aR[i][2] + rbv.z + cbv.z + d2 * hv.z;
      av.w = aR[i][3] + rbv.w + cbv.w + d2 * hv.w;
      *(float4*)(agg + n * 64 + hg) = av;
    }
  }
}

// ---------------- CSR gather: agg[n] += sum_e wgt[e] * hW[col[e]] ----------------
// One 64-lane wave per dst node; lane = h. ILP-4: predicated 4-wide batches keep
// 4 LLC loads in flight even on the remainder. On the last layer, fuse the decode
// GEMV: Xo[n] = relu(X_final[n]) . decW (one coalesced write per wave, no atomics).

__global__ __launch_bounds__(256) void k_gather(const int* __restrict__ rowptr, const int* __restrict__ col,
                                                const float* __restrict__ wgt, const float* __restrict__ hW,
                                                float* __restrict__ agg,
                                                const float* __restrict__ decW, float* __restrict__ Xo,
                                                int last) {
  int lane = threadIdx.x & 63;
  int n = __builtin_amdgcn_readfirstlane(blockIdx.x * 4 + (threadIdx.x >> 6));
  int st = rowptr[n];
  int en = rowptr[n + 1];
  float a0 = 0.f, a1 = 0.f, a2 = 0.f, a3 = 0.f;
  int el = en - 1;
  for (int e = st; e < en; e += 4) {
    int e1 = (e + 1 < en) ? e + 1 : el;
    int e2 = (e + 2 < en) ? e + 2 : el;
    int e3 = (e + 3 < en) ? e + 3 : el;
    int s0 = col[e], s1 = col[e1], s2 = col[e2], s3 = col[e3];
    float w0 = wgt[e];
    float w1 = (e + 1 < en) ? wgt[e1] : 0.f;
    float w2 = (e + 2 < en) ? wgt[e2] : 0.f;
    float w3 = (e + 3 < en) ? wgt[e3] : 0.f;
    a0 += w0 * hW[s0 * 64 + lane];
    a1 += w1 * hW[s1 * 64 + lane];
    a2 += w2 * hW[s2 * 64 + lane];
    a3 += w3 * hW[s3 * 64 + lane];
  }
  float acc = agg[n * 64 + lane] + (a0 + a1) + (a2 + a3);
  agg[n * 64 + lane] = acc;
  if (last) {
    float v = fmaxf(acc, 0.f) * decW[lane];
#pragma unroll
    for (int off = 32; off > 0; off >>= 1) v += __shfl_down(v, off, 64);
    if (lane == 0) Xo[n] = v;
  }
}

// ---------------- graph pooling: out[g] = sum Xo[gptr[g]:gptr[g+1]] + cnt*decb ----------------

__global__ __launch_bounds__(256) void k_pool(const float* __restrict__ Xo, const int* __restrict__ gptr,
                                              const float* __restrict__ decb, float* __restrict__ out) {
  __shared__ float part[4];
  int g = blockIdx.x;
  int t = threadIdx.x;
  int st = gptr[g], en = gptr[g + 1];
  float v = 0.f;
  for (int i = st + t; i < en; i += 256) v += Xo[i];
#pragma unroll
  for (int off = 32; off > 0; off >>= 1) v += __shfl_down(v, off, 64);
  if ((t & 63) == 0) part[t >> 6] = v;
  __syncthreads();
  if (t == 0) out[g] = part[0] + part[1] + part[2] + part[3] + (float)(en - st) * decb[0];
}

// ---------------- launch ----------------

extern "C" void kernel_launch(void* const* d_in, const int* in_sizes, int n_in,
                              void* d_out, int out_size, void* d_ws, size_t ws_size,
                              hipStream_t stream) {
  (void)in_sizes; (void)n_in; (void)out_size; (void)ws_size;
  const float* x     = (const float*)d_in[0];
  const float* pos   = (const float*)d_in[1];
  const int*   ei    = (const int*)d_in[2];
  const int*   batch = (const int*)d_in[3];
  const float* encW  = (const float*)d_in[4];
  const float* encb  = (const float*)d_in[5];
  const float* convW = (const float*)d_in[6];
  const float* convb = (const float*)d_in[7];
  const float* resW  = (const float*)d_in[8];
  const float* resb  = (const float*)d_in[9];
  const float* decW  = (const float*)d_in[10];
  const float* decb  = (const float*)d_in[11];
  float* out = (float*)d_out;

  const int* src = ei;       // edge_index[0]
  const int* dst = ei + NE;  // edge_index[1]

  // workspace layout (4-byte elems)
  float* ws     = (float*)d_ws;
  float* dinv   = ws;                        // [NPAD]
  int*   deg    = (int*)(ws + NPAD);         // [NPAD]
  int*   rowptr = (int*)(ws + 2 * NPAD);     // [NPAD+1]
  int*   cursor = (int*)(ws + 3 * NPAD + 256);
  int*   bsum   = (int*)(ws + 4 * NPAD + 256);  // [256]
  int*   gptr   = (int*)(ws + 4 * NPAD + 512);  // [NG+1]
  float* Xo     = (float*)(gptr + 512);         // [NN]
  int*   col    = (int*)(Xo + NPAD);            // [NE]
  float* wgt    = (float*)(col + NE);           // [NE]
  float* bufA   = wgt + NE;                     // [NN*NH]
  float* bufB   = bufA + NN * NH;
  float* bufC   = bufB + NN * NH;

  hipMemsetAsync(deg, 0, NPAD * sizeof(int), stream);

  k_hist<<<(NE + 255) / 256, 256, 0, stream>>>(dst, deg);
  k_dinv<<<(NN + 255) / 256, 256, 0, stream>>>(deg, dinv);
  k_scanA<<<NPAD / 256, 256, 0, stream>>>(deg, bsum);
  k_scanB<<<1, 256, 0, stream>>>(bsum);
  k_scanC<<<NPAD / 256, 256, 0, stream>>>(deg, bsum, rowptr, cursor);
  k_fill<<<(NE + 255) / 256, 256, 0, stream>>>(src, dst, dinv, cursor, col, wgt);
  k_gptr<<<(NN + 255) / 256, 256, 0, stream>>>(batch, gptr);

  k_encoder<<<(NN + 3) / 4, 256, 0, stream>>>(x, pos, encW, encb, bufA);

  float* Xc = bufA;
  float* hWb = bufB;
  float* aggb = bufC;
  for (int l = 0; l < 5; l++) {
    k_gemm_dual<<<(NN + 127) / 128, 256, 0, stream>>>(Xc, convW, resW, convb, resb, dinv, hWb, aggb, l > 0 ? 1 : 0);
    k_gather<<<NN / 4, 256, 0, stream>>>(rowptr, col, wgt, hWb, aggb, decW, Xo, l == 4 ? 1 : 0);
    float* tmp = Xc; Xc = aggb; aggb = hWb; hWb = tmp;
  }
  k_pool<<<NG, 256, 0, stream>>>(Xo, gptr, decb, out);
}

// Round 4
// 454.926 us; speedup vs baseline: 2.6587x; 1.0289x over previous
//
#include <hip/hip_runtime.h>

#define NN 50000
#define NE 800000
#define NH 64
#define NG 500
#define NPAD 50176   // 196*256

// ---------------- degree histogram / normalization ----------------

__global__ __launch_bounds__(256) void k_hist(const int* __restrict__ dst, int* __restrict__ deg) {
  int e = blockIdx.x * 256 + threadIdx.x;
  if (e < NE) atomicAdd(&deg[dst[e]], 1);
}

__global__ __launch_bounds__(256) void k_dinv(const int* __restrict__ deg, float* __restrict__ dinv) {
  int i = blockIdx.x * 256 + threadIdx.x;
  if (i < NN) dinv[i] = rsqrtf((float)(deg[i] + 1));  // +1 self-loop
}

// ---------------- CSR build: scan + fill ----------------

__global__ __launch_bounds__(256) void k_scanA(const int* __restrict__ deg, int* __restrict__ bsum) {
  __shared__ int part[4];
  int i = blockIdx.x * 256 + threadIdx.x;
  int v = deg[i];  // region zeroed to NPAD
#pragma unroll
  for (int off = 32; off > 0; off >>= 1) v += __shfl_down(v, off, 64);
  if ((threadIdx.x & 63) == 0) part[threadIdx.x >> 6] = v;
  __syncthreads();
  if (threadIdx.x == 0) bsum[blockIdx.x] = part[0] + part[1] + part[2] + part[3];
}

__global__ __launch_bounds__(256) void k_scanB(int* __restrict__ bsum) {
  __shared__ int s[256];
  int t = threadIdx.x;
  int v = (t < 196) ? bsum[t] : 0;
  s[t] = v;
  __syncthreads();
#pragma unroll
  for (int off = 1; off < 256; off <<= 1) {
    int x = (t >= off) ? s[t - off] : 0;
    __syncthreads();
    s[t] += x;
    __syncthreads();
  }
  if (t < 196) bsum[t] = s[t] - v;  // exclusive
}

__global__ __launch_bounds__(256) void k_scanC(const int* __restrict__ deg, const int* __restrict__ bsum,
                                               int* __restrict__ rowptr, int* __restrict__ cursor) {
  __shared__ int s[256];
  int t = threadIdx.x;
  int i = blockIdx.x * 256 + t;
  int v = deg[i];
  s[t] = v;
  __syncthreads();
#pragma unroll
  for (int off = 1; off < 256; off <<= 1) {
    int x = (t >= off) ? s[t - off] : 0;
    __syncthreads();
    s[t] += x;
    __syncthreads();
  }
  int row = bsum[blockIdx.x] + s[t] - v;  // exclusive prefix; deg[i>=NN]==0 so rowptr[NN]==NE
  rowptr[i] = row;
  cursor[i] = row;
}

__global__ __launch_bounds__(256) void k_fill(const int* __restrict__ src, const int* __restrict__ dst,
                                              int* __restrict__ cursor, int* __restrict__ col) {
  int e = blockIdx.x * 256 + threadIdx.x;
  if (e < NE) {
    int d = dst[e];
    int p = atomicAdd(&cursor[d], 1);
    col[p] = src[e];
  }
}

// ---------------- graph segment pointers from sorted batch (no atomics) ----------------

__global__ __launch_bounds__(256) void k_gptr(const int* __restrict__ batch, int* __restrict__ gptr) {
  int i = blockIdx.x * 256 + threadIdx.x;
  if (i >= NN) return;
  int bi = batch[i];
  int bp = (i > 0) ? batch[i - 1] : -1;
  for (int g = bp + 1; g <= bi; g++) gptr[g] = i;
  if (i == NN - 1) {
    for (int g = bi + 1; g <= NG; g++) gptr[g] = NN;
  }
}

// ---------------- encoder: X0 = [x|pos] @ enc_W + enc_b ----------------

__global__ __launch_bounds__(256) void k_encoder(const float* __restrict__ x, const float* __restrict__ pos,
                                                 const float* __restrict__ W, const float* __restrict__ b,
                                                 float* __restrict__ X0) {
  __shared__ float Ws[16 * 64];
  __shared__ float bs[64];
  int t = threadIdx.x;
  for (int i = t; i < 1024; i += 256) Ws[i] = W[i];
  if (t < 64) bs[t] = b[t];
  __syncthreads();
  int n = blockIdx.x * 4 + (t >> 6);
  int h = t & 63;
  if (n >= NN) return;
  float acc = bs[h];
#pragma unroll
  for (int f = 0; f < 14; f++) acc += x[n * 14 + f] * Ws[f * 64 + h];
  acc += pos[n * 2 + 0] * Ws[14 * 64 + h];
  acc += pos[n * 2 + 1] * Ws[15 * 64 + h];
  X0[n * 64 + h] = acc;
}

// ---------------- fused dual GEMM + epilogue ----------------
// hWs = dinv[n] * (relu?(X) @ conv_W)            (dinv folded in: gather sums hWs)
// agg = relu?(X) @ res_W + res_b + conv_b + dinv[n] * hWs[n]   (self-loop folded in)

__global__ __launch_bounds__(256) void k_gemm_dual(const float* __restrict__ Xin,
                                                   const float* __restrict__ Wc, const float* __restrict__ Wr,
                                                   const float* __restrict__ cb, const float* __restrict__ rb,
                                                   const float* __restrict__ dinv,
                                                   float* __restrict__ hWs, float* __restrict__ agg,
                                                   int apply_relu) {
  __shared__ float Xs[128 * 64];
  __shared__ float Wcs[64 * 64];
  __shared__ float Wrs[64 * 64];
  int t = threadIdx.x;
  for (int i = t; i < 4096; i += 256) { Wcs[i] = Wc[i]; Wrs[i] = Wr[i]; }
  int n0 = blockIdx.x * 128;
#pragma unroll
  for (int i = 0; i < 8; i++) {
    int idx = t + i * 256;        // float4 index in 128x64 tile (2048 total)
    int n = idx >> 4;             // 16 float4 per row
    int kg = (idx & 15) << 2;     // k offset of float4
    float4 v = make_float4(0.f, 0.f, 0.f, 0.f);
    int gn = n0 + n;
    if (gn < NN) v = *(const float4*)(Xin + gn * 64 + kg);
    if (apply_relu) {
      v.x = fmaxf(v.x, 0.f); v.y = fmaxf(v.y, 0.f);
      v.z = fmaxf(v.z, 0.f); v.w = fmaxf(v.w, 0.f);
    }
    int sw = ((n >> 3) & 7) << 2;  // bank swizzle (float4-preserving)
    *(float4*)(Xs + n * 64 + (kg ^ sw)) = v;
  }
  __syncthreads();

  int hg = (t & 15) << 2;   // h0 (4 consecutive h)
  int ng = t >> 4;          // node group
  int nb = ng << 3;         // local node base (8 nodes)
  int swz = (ng & 7) << 2;  // matches write swizzle: rows nb..nb+7 all have row>>3 == ng

  float aC[8][4] = {};
  float aR[8][4] = {};
#pragma unroll 4
  for (int k = 0; k < 64; k++) {
    float4 wc = *(const float4*)(Wcs + k * 64 + hg);
    float4 wr = *(const float4*)(Wrs + k * 64 + hg);
    int kk = k ^ swz;
#pragma unroll
    for (int i = 0; i < 8; i++) {
      float xv = Xs[(nb + i) * 64 + kk];
      aC[i][0] += xv * wc.x; aC[i][1] += xv * wc.y; aC[i][2] += xv * wc.z; aC[i][3] += xv * wc.w;
      aR[i][0] += xv * wr.x; aR[i][1] += xv * wr.y; aR[i][2] += xv * wr.z; aR[i][3] += xv * wr.w;
    }
  }

  float4 cbv = *(const float4*)(cb + hg);
  float4 rbv = *(const float4*)(rb + hg);
#pragma unroll
  for (int i = 0; i < 8; i++) {
    int n = n0 + nb + i;
    if (n < NN) {
      float dv = dinv[n];
      float4 hv;
      hv.x = dv * aC[i][0]; hv.y = dv * aC[i][1]; hv.z = dv * aC[i][2]; hv.w = dv * aC[i][3];
      *(float4*)(hWs + n * 64 + hg) = hv;
      float4 av;
      av.x = aR[i][0] + rbv.x + cbv.x + dv * hv.x;
      av.y = aR[i][1] + rbv.y + cbv.y + dv * hv.y;
      av.z = aR[i][2] + rbv.z + cbv.z + dv * hv.z;
      av.w = aR[i][3] + rbv.w + cbv.w + dv * hv.w;
      *(float4*)(agg + n * 64 + hg) = av;
    }
  }
}

// ---------------- CSR gather: agg[n] += dinv[n] * sum_e hWs[col[e]] ----------------
// One 64-lane wave per dst node; lane = h. The whole adjacency row's col indices are
// loaded with ONE coalesced 64-lane load, then shuffle-broadcast (register-only) —
// the per-edge address chain disappears and 8 hWs loads stay in flight per batch.
// Last layer fuses decode GEMV: Xo[n] = relu(X_final[n]) . decW.

__global__ __launch_bounds__(256) void k_gather(const int* __restrict__ rowptr, const int* __restrict__ col,
                                                const float* __restrict__ dinv, const float* __restrict__ hWs,
                                                float* __restrict__ agg,
                                                const float* __restrict__ decW, float* __restrict__ Xo,
                                                int last) {
  int lane = threadIdx.x & 63;
  int n = __builtin_amdgcn_readfirstlane(blockIdx.x * 4 + (threadIdx.x >> 6));
  int st = rowptr[n];
  int en = rowptr[n + 1];
  int deg = en - st;
  float acc = 0.f;
  for (int base = 0; base < deg; base += 64) {
    int cnt = deg - base;
    if (cnt > 64) cnt = 64;
    int li = lane < cnt ? lane : cnt - 1;
    int colv = col[st + base + li];  // one coalesced row-load of up to 64 indices
    for (int j = 0; j < cnt; j += 8) {
      int c = cnt - j;  // remaining (>=1)
      int s0 = __shfl(colv, j, 64);
      int s1 = __shfl(colv, c > 1 ? j + 1 : j, 64);
      int s2 = __shfl(colv, c > 2 ? j + 2 : j, 64);
      int s3 = __shfl(colv, c > 3 ? j + 3 : j, 64);
      int s4 = __shfl(colv, c > 4 ? j + 4 : j, 64);
      int s5 = __shfl(colv, c > 5 ? j + 5 : j, 64);
      int s6 = __shfl(colv, c > 6 ? j + 6 : j, 64);
      int s7 = __shfl(colv, c > 7 ? j + 7 : j, 64);
      float v0 = hWs[s0 * 64 + lane];
      float v1 = hWs[s1 * 64 + lane];
      float v2 = hWs[s2 * 64 + lane];
      float v3 = hWs[s3 * 64 + lane];
      float v4 = hWs[s4 * 64 + lane];
      float v5 = hWs[s5 * 64 + lane];
      float v6 = hWs[s6 * 64 + lane];
      float v7 = hWs[s7 * 64 + lane];
      acc += v0;
      acc += (c > 1) ? v1 : 0.f;
      acc += (c > 2) ? v2 : 0.f;
      acc += (c > 3) ? v3 : 0.f;
      acc += (c > 4) ? v4 : 0.f;
      acc += (c > 5) ? v5 : 0.f;
      acc += (c > 6) ? v6 : 0.f;
      acc += (c > 7) ? v7 : 0.f;
    }
  }
  float r = agg[n * 64 + lane] + dinv[n] * acc;
  agg[n * 64 + lane] = r;
  if (last) {
    float v = fmaxf(r, 0.f) * decW[lane];
#pragma unroll
    for (int off = 32; off > 0; off >>= 1) v += __shfl_down(v, off, 64);
    if (lane == 0) Xo[n] = v;
  }
}

// ---------------- graph pooling: out[g] = sum Xo[gptr[g]:gptr[g+1]] + cnt*decb ----------------

__global__ __launch_bounds__(256) void k_pool(const float* __restrict__ Xo, const int* __restrict__ gptr,
                                              const float* __restrict__ decb, float* __restrict__ out) {
  __shared__ float part[4];
  int g = blockIdx.x;
  int t = threadIdx.x;
  int st = gptr[g], en = gptr[g + 1];
  float v = 0.f;
  for (int i = st + t; i < en; i += 256) v += Xo[i];
#pragma unroll
  for (int off = 32; off > 0; off >>= 1) v += __shfl_down(v, off, 64);
  if ((t & 63) == 0) part[t >> 6] = v;
  __syncthreads();
  if (t == 0) out[g] = part[0] + part[1] + part[2] + part[3] + (float)(en - st) * decb[0];
}

// ---------------- launch ----------------

extern "C" void kernel_launch(void* const* d_in, const int* in_sizes, int n_in,
                              void* d_out, int out_size, void* d_ws, size_t ws_size,
                              hipStream_t stream) {
  (void)in_sizes; (void)n_in; (void)out_size; (void)ws_size;
  const float* x     = (const float*)d_in[0];
  const float* pos   = (const float*)d_in[1];
  const int*   ei    = (const int*)d_in[2];
  const int*   batch = (const int*)d_in[3];
  const float* encW  = (const float*)d_in[4];
  const float* encb  = (const float*)d_in[5];
  const float* convW = (const float*)d_in[6];
  const float* convb = (const float*)d_in[7];
  const float* resW  = (const float*)d_in[8];
  const float* resb  = (const float*)d_in[9];
  const float* decW  = (const float*)d_in[10];
  const float* decb  = (const float*)d_in[11];
  float* out = (float*)d_out;

  const int* src = ei;       // edge_index[0]
  const int* dst = ei + NE;  // edge_index[1]

  // workspace layout (4-byte elems)
  float* ws     = (float*)d_ws;
  float* dinv   = ws;                           // [NPAD]
  int*   deg    = (int*)(ws + NPAD);            // [NPAD]
  int*   rowptr = (int*)(ws + 2 * NPAD);        // [NPAD+1]
  int*   cursor = (int*)(ws + 3 * NPAD + 256);  // [NPAD]
  int*   bsum   = (int*)(ws + 4 * NPAD + 256);  // [256]
  int*   gptr   = (int*)(ws + 4 * NPAD + 512);  // [NG+1]
  float* Xo     = (float*)(ws + 4 * NPAD + 1024);  // [NPAD]
  int*   col    = (int*)(ws + 5 * NPAD + 1024);    // [NE]
  float* bufA   = (float*)(col + NE);              // [NN*NH]
  float* bufB   = bufA + NN * NH;
  float* bufC   = bufB + NN * NH;

  hipMemsetAsync(deg, 0, NPAD * sizeof(int), stream);

  k_hist<<<(NE + 255) / 256, 256, 0, stream>>>(dst, deg);
  k_dinv<<<(NN + 255) / 256, 256, 0, stream>>>(deg, dinv);
  k_scanA<<<NPAD / 256, 256, 0, stream>>>(deg, bsum);
  k_scanB<<<1, 256, 0, stream>>>(bsum);
  k_scanC<<<NPAD / 256, 256, 0, stream>>>(deg, bsum, rowptr, cursor);
  k_fill<<<(NE + 255) / 256, 256, 0, stream>>>(src, dst, cursor, col);
  k_gptr<<<(NN + 255) / 256, 256, 0, stream>>>(batch, gptr);

  k_encoder<<<(NN + 3) / 4, 256, 0, stream>>>(x, pos, encW, encb, bufA);

  float* Xc = bufA;
  float* hWb = bufB;
  float* aggb = bufC;
  for (int l = 0; l < 5; l++) {
    k_gemm_dual<<<(NN + 127) / 128, 256, 0, stream>>>(Xc, convW, resW, convb, resb, dinv, hWb, aggb, l > 0 ? 1 : 0);
    k_gather<<<NN / 4, 256, 0, stream>>>(rowptr, col, dinv, hWb, aggb, decW, Xo, l == 4 ? 1 : 0);
    float* tmp = Xc; Xc = aggb; aggb = hWb; hWb = tmp;
  }
  k_pool<<<NG, 256, 0, stream>>>(Xo, gptr, decb, out);
}